// Round 16
// baseline (123.237 us; speedup 1.0000x reference)
//
#include <hip/hip_runtime.h>
#include <cmath>

// Kalman_Smooth_Gradient: B=4096 seqs, T=128 steps, 6-state EKF + RTS + loss.
// Round 16: r13 (best measured chains: 192 blocks x 64 thr, zT-coalesced,
// 51us) with the ztrans dispatch folded INTO chains via r14's proven LDS
// staging pattern: lanes-along-t loads (12-line bursts, full MLP) + stride-65
// conflict-free LDS writes. 3 dispatches total: memset, chains, det.

namespace {

constexpr int B = 4096;
constexpr int T = 128;
constexpr int NT = B * 3;           // 12288 filter chains
constexpr int NBLK1 = 192;          // chains blocks (64 per filter)
constexpr int TRIPLES = 126 * B;    // det terms, n = 2..127
constexpr float DTc     = 1.0f / 120.0f;
constexpr float TWO_PIc = 6.28318530717958647692f;
constexpr float PI_1_5  = 4.71238898038468985769f;
constexpr float INV_2PI = 0.15915494309189533577f;

__device__ __forceinline__ float frcp(float x) { return __builtin_amdgcn_rcpf(x); }

__device__ __forceinline__ float fast_tanh(float x) {
  float e = __expf(2.0f * x);
  return 1.0f - 2.0f * frcp(e + 1.0f);
}
__device__ __forceinline__ float sigmoidf(float x) {
  return frcp(1.0f + __expf(-x));
}

// ---------------------------------------------------------------------------
// chains_kernel: one wave per block; block = (filter f) x (64 seqs).
// hist4: [T][NT] float4 (p,v,P00,P01); hist1: [T][NT] float P11;
// aqA: [(n*3+f)*B + seq] float a (valid n = 2..T-1).
// LDS zl[t*65 + s]: this block's z-component plane, conflict-free.
// ---------------------------------------------------------------------------
__global__ __launch_bounds__(64, 1) void chains_kernel(
    const float* __restrict__ params, const float* __restrict__ covp,
    const float* __restrict__ init_states, const float* __restrict__ z,
    float4* __restrict__ hist4, float* __restrict__ hist1,
    float* __restrict__ aqA, float* __restrict__ out) {
  const int lane = threadIdx.x;
  const int blk = blockIdx.x;
  const int f = blk >> 6;           // 0=x, 1=y, 2=theta (wave-uniform)
  const int g = blk & 63;
  const int seq = g * 64 + lane;
  const int fi = f * B + seq;       // chain id (lane-consecutive -> coalesced)

  __shared__ float zl[128 * 65];    // 33.3 KB, [t][s], stride 65 (bank-safe)

  // ---- stage z: lanes-along-t (12-line bursts), conflict-free LDS writes --
  {
#pragma unroll 8
    for (int s2 = 0; s2 < 64; s2++) {
      const float* zb = z + (size_t)(g * 64 + s2) * (T * 3) + f;
      const float v0 = zb[(size_t)lane * 3];
      const float v1 = zb[(size_t)(64 + lane) * 3];
      zl[lane * 65 + s2] = v0;
      zl[(64 + lane) * 65 + s2] = v1;
    }
  }
  __syncthreads();

  // ---- shared scalars ----
  const float friction = (fast_tanh(params[0]) + 1.0f) * 0.01f;
  const float damping  = (fast_tanh(params[1]) + 1.0f) * 0.01f;
  float cp[7];
#pragma unroll
  for (int i = 0; i < 7; i++) cp[i] = sigmoidf(covp[i]);
  const float dcoef = 1.0f - DTc * damping;
  const bool isTH = (f == 2);                 // wave-uniform branch
  const float q0 = isTH ? cp[5] : cp[3];
  const float q1 = isTH ? cp[6] : cp[4];
  const float r  = cp[f];

  // ---- init ----
  const int pidx = (f == 0) ? 0 : (f == 1) ? 1 : 4;
  const int vidx = (f == 0) ? 2 : (f == 1) ? 3 : 5;
  float p = init_states[seq * 6 + pidx];
  float v = init_states[seq * 6 + vidx];
  float P00 = 0.01f, P01 = 0.0f, P11 = 0.01f;

  float qacc = 0.0f;  // local quad-part accumulator (a * e^2)

  // =========================== forward ===========================
#pragma unroll 8
  for (int t = 0; t < T; t++) {
    const float zc = zl[t * 65 + lane];

    float gg, tv;
    if (!isTH) {
      const float th = fast_tanh(100.0f * v);
      tv = v - DTc * (damping * v + friction * th);
      gg = 1.0f - DTc * (damping + 100.0f * friction * (1.0f - th * th));
    } else {
      tv = dcoef * v;
      gg = dcoef;
    }
    const float tp = p + DTc * v;
    const float u = P01 + DTc * P11;
    const float Pp00 = P00 + DTc * P01 + DTc * u + q0;
    const float Pp01 = gg * u;
    const float Pp11 = gg * (gg * P11) + q1;
    const float iS = frcp(Pp00 + r);
    const float K0 = Pp00 * iS;
    const float K1 = Pp01 * iS;
    float e = zc - tp;
    if (isTH) e = e - TWO_PIc * rintf(e * INV_2PI);  // _wrap
    p = tp + K0 * e;
    v = tv + K1 * e;
    const float om = 1.0f - K0;
    P00 = om * Pp00;
    P01 = om * Pp01;
    P11 = Pp11 - K1 * Pp01;

    hist4[(size_t)t * NT + fi] = make_float4(p, v, P00, P01);
    hist1[(size_t)t * NT + fi] = P11;
  }

  // ---- terminal term n = T-1 (smoothed == filtered) ----
  {
    const float zlv = zl[(T - 1) * 65 + lane];
    float e = zlv - p;
    if (isTH) {
      if (e >  PI_1_5) e -= TWO_PIc;
      if (e < -PI_1_5) e += TWO_PIc;
    }
    const float a = P00 + r;
    qacc += a * e * e;
    aqA[(size_t)((T - 1) * 3 + f) * B + seq] = a;
  }

  // =========================== backward ===========================
  float sp_ = p, sv_ = v, Ps00 = P00, Ps01 = P01, Ps11 = P11;

  // depth-8 rolling prefetch of hist; iteration i -> n = 126 - i; padded to
  // 128 iters (n = 126..-1); n < 2 iterations compute garbage, never store.
  float4 h4b[8];
  float h1b[8];
#pragma unroll
  for (int i = 0; i < 8; i++) {
    const int n2 = 126 - i;
    h4b[i] = hist4[(size_t)n2 * NT + fi];
    h1b[i] = hist1[(size_t)n2 * NT + fi];
  }

#pragma unroll 8
  for (int i = 0; i < 128; i++) {
    const int n = 126 - i;
    const int sl = i & 7;
    const float4 h4 = h4b[sl];
    const float h1 = h1b[sl];
    const int nz = (n < 2) ? 2 : n;
    const float zn_ = zl[nz * 65 + lane];
    const int nf = (n >= 10) ? (n - 8) : 2;  // clamped prefetch target
    h4b[sl] = hist4[(size_t)nf * NT + fi];
    h1b[sl] = hist1[(size_t)nf * NT + fi];

    const float fp = h4.x, fv = h4.y, f00 = h4.z, f01 = h4.w, f11 = h1;

    float gg, tv;
    if (!isTH) {
      const float th = fast_tanh(100.0f * fv);
      tv = fv - DTc * (damping * fv + friction * th);
      gg = 1.0f - DTc * (damping + 100.0f * friction * (1.0f - th * th));
    } else {
      tv = dcoef * fv;
      gg = dcoef;
    }
    const float tp = fp + DTc * fv;
    const float u = f01 + DTc * f11;
    const float Pp00 = f00 + DTc * f01 + DTc * u + q0;
    const float Pp01 = gg * u;
    const float Pp11 = gg * (gg * f11) + q1;

    // G = P_f F^T Pp^{-1} (closed-form 2x2)
    const float idet = frcp(Pp00 * Pp11 - Pp01 * Pp01);
    const float W00 = f00, W01 = DTc * f00 + gg * f01;
    const float W10 = f01, W11 = DTc * f01 + gg * f11;
    const float G00 = (W00 * Pp11 - W01 * Pp01) * idet;
    const float G01 = (W01 * Pp00 - W00 * Pp01) * idet;
    const float G10 = (W10 * Pp11 - W11 * Pp01) * idet;
    const float G11 = (W11 * Pp00 - W10 * Pp01) * idet;

    const float ds0 = sp_ - tp, ds1 = sv_ - tv;
    const float np = fp + G00 * ds0 + G01 * ds1;
    const float nv = fv + G10 * ds0 + G11 * ds1;

    const float M00 = Ps00 - Pp00, M01 = Ps01 - Pp01, M11 = Ps11 - Pp11;
    const float GM00 = G00 * M00 + G01 * M01, GM01 = G00 * M01 + G01 * M11;
    const float GM10 = G10 * M00 + G11 * M01, GM11 = G10 * M01 + G11 * M11;
    Ps00 = f00 + GM00 * G00 + GM01 * G01;
    Ps01 = f01 + GM00 * G10 + GM01 * G11;
    Ps11 = f11 + GM10 * G10 + GM11 * G11;
    sp_ = np;
    sv_ = nv;

    if (n >= 2) {
      const float a = Ps00 + r;
      float e = zn_ - np;
      if (isTH) {
        if (e >  PI_1_5) e -= TWO_PIc;
        if (e < -PI_1_5) e += TWO_PIc;
      }
      qacc += a * e * e;
      aqA[(size_t)(n * 3 + f) * B + seq] = a;
    }
  }

  // ---- wave reduce + one atomic per block ----
#pragma unroll
  for (int off = 32; off > 0; off >>= 1) qacc += __shfl_down(qacc, off);
  if (lane == 0) atomicAdd(out, qacc);
}

// ---------------------------------------------------------------------------
// det_kernel: sum over (seq, n=2..127) of ax*ay*at. Coalesced triple loads.
// ---------------------------------------------------------------------------
__global__ __launch_bounds__(256, 4) void det_kernel(
    const float* __restrict__ aqA, float* __restrict__ out) {
  const int tid0 = blockIdx.x * 256 + threadIdx.x;
  const int stride = gridDim.x * 256;
  float part = 0.0f;
  for (int idx = tid0; idx < TRIPLES; idx += stride) {
    const int n2 = 2 + (idx >> 12);       // idx / B
    const int seq = idx & (B - 1);
    const float a0 = aqA[(size_t)(n2 * 3 + 0) * B + seq];
    const float a1 = aqA[(size_t)(n2 * 3 + 1) * B + seq];
    const float a2 = aqA[(size_t)(n2 * 3 + 2) * B + seq];
    part += a0 * a1 * a2;
  }
#pragma unroll
  for (int off = 32; off > 0; off >>= 1) part += __shfl_down(part, off);
  __shared__ float red[4];
  if ((threadIdx.x & 63) == 0) red[threadIdx.x >> 6] = part;
  __syncthreads();
  if (threadIdx.x == 0) atomicAdd(out, red[0] + red[1] + red[2] + red[3]);
}

}  // namespace

extern "C" void kernel_launch(void* const* d_in, const int* in_sizes, int n_in,
                              void* d_out, int out_size, void* d_ws, size_t ws_size,
                              hipStream_t stream) {
  const float* params      = (const float*)d_in[0];
  const float* covp        = (const float*)d_in[1];
  const float* init_states = (const float*)d_in[2];
  const float* z           = (const float*)d_in[3];
  float* out = (float*)d_out;

  const size_t hist4B = (size_t)T * NT * sizeof(float4);   // 25.2 MB
  const size_t hist1B = (size_t)T * NT * sizeof(float);    //  6.3 MB
  const size_t aqB    = (size_t)T * 3 * B * sizeof(float); //  6.3 MB
  const size_t needBytes = hist4B + hist1B + aqB;          // 37.8 MB

  hipMemsetAsync(d_out, 0, sizeof(float), stream);

  if (ws_size >= needBytes) {
    float4* hist4 = (float4*)d_ws;
    float*  hist1 = (float*)((char*)d_ws + hist4B);
    float*  aqA   = (float*)((char*)d_ws + hist4B + hist1B);
    chains_kernel<<<NBLK1, 64, 0, stream>>>(params, covp, init_states, z,
                                            hist4, hist1, aqA, out);
    det_kernel<<<504, 256, 0, stream>>>(aqA, out);
  }
}